// Round 7
// baseline (25.397 us; speedup 1.0000x reference)
//
#include <hip/hip_runtime.h>
#include <hip/hip_bf16.h>

namespace {

constexpr int KIN  = 32;    // IN_CH
constexpr int KOUT = 64;    // OUT_CH
constexpr int KW   = 9;     // KERNEL
constexpr int KPAD = 4;     // PADDING
constexpr int LIN  = 2048;
constexpr int KTOT = 2592;  // 9 taps * 288 features

typedef __bf16 bf16x8 __attribute__((ext_vector_type(8)));
typedef float  f32x4  __attribute__((ext_vector_type(4)));

__device__ __forceinline__ unsigned short f2bf(float x) {
    unsigned int u = __float_as_uint(x);
    u += 0x7FFFu + ((u >> 16) & 1u);   // RNE
    return (unsigned short)(u >> 16);
}

// ---- kernel 1: weights -> MFMA-fragment order ----
// Wf[((ch*4+m)*64 + hi*16+lo)*8 + e] = W[o=m*16+lo][kappa=ch*32+hi*8+e]
__global__ __launch_bounds__(256) void kan_wprep(const float* __restrict__ base_w,
                                                 const float* __restrict__ spline_w,
                                                 const float* __restrict__ spline_scaler,
                                                 unsigned short* __restrict__ Wf) {
    int t = blockIdx.x * 256 + threadIdx.x;
    if (t >= KOUT * KIN * KW) return;
    int k = t % KW;
    int i = (t / KW) % KIN;
    int o = t / (KW * KIN);
    float sc = spline_scaler[t];
    int m  = o >> 4;
    int lo = o & 15;
#pragma unroll
    for (int c = 0; c < 9; ++c) {
        float val = (c == 0) ? base_w[t] : spline_w[(size_t)t * 8 + (c - 1)] * sc;
        int kappa = k * 288 + i * 9 + c;
        int ch = kappa >> 5;
        int hi = (kappa & 31) >> 3;
        int e  = kappa & 7;
        Wf[((size_t)(ch * 4 + m) * 64 + hi * 16 + lo) * 8 + e] = f2bf(val);
    }
}

// ---- kernel 2: fused features + pipelined quadrant/2-way-split-K MFMA GEMM ----
constexpr int BN     = 64;
constexpr int TROW   = 72;    // BN + KW - 1
constexpr int F2COLS = 296;   // 592B rows; stride 148 dw = 20 mod 32 (2-way max, free)

__global__ __launch_bounds__(512, 4) void kan_fused(const float* __restrict__ x,
                                                    const unsigned short* __restrict__ Wf,
                                                    float* __restrict__ out) {
    __shared__ __align__(16) char smem[TROW * F2COLS * 2];   // f2t 42624 B / red 16 KB
    unsigned short* f2t = (unsigned short*)smem;

    int tid  = threadIdx.x;
    int lane = tid & 63;
    int wv   = tid >> 6;          // 0..7
    int lo = lane & 15, hi = lane >> 4;
    int ks = wv >> 2;             // 0..1 : K-half
    int q  = wv & 3;              // 0..3 : output quadrant
    int mq = q >> 1;              // o-half (32)
    int nq = q & 1;               // l-half (32)

    int blk = blockIdx.x;
    int b   = blk >> 5;
    int l0  = (blk & 31) * BN;

    // ---- hoist x loads (long latency) ahead of LDS zeroing ----
    float vv[5];
#pragma unroll
    for (int p = 0; p < 5; ++p) {
        int unit = p * 512 + tid;
        bool ok = unit < TROW * KIN;
        int i = unit / TROW;
        int r = unit - i * TROW;
        int gx = l0 + r - KPAD;
        vv[p] = 0.f;
        if (ok && gx >= 0 && gx < LIN) vv[p] = x[((size_t)b * KIN + i) * LIN + gx];
    }

    // ---- zero f2t (2664 x 16B) ----
    {
        f32x4 z = (f32x4){0.f, 0.f, 0.f, 0.f};
        for (int c = tid; c < TROW * F2COLS / 8; c += 512)
            *(f32x4*)(f2t + (size_t)c * 8) = z;
    }
    __syncthreads();

    // ---- features: silu + closed-form cubic B-spline, scatter to LDS ----
#pragma unroll
    for (int p = 0; p < 5; ++p) {
        int unit = p * 512 + tid;
        bool ok = unit < TROW * KIN;
        int i = unit / TROW;
        int r = unit - i * TROW;
        float v = vv[p];
        if (ok) {
            unsigned short* row = f2t + (size_t)r * F2COLS + i * 9;
            row[0] = f2bf(v / (1.f + __expf(-v)));             // silu
            float t5 = (v + 2.2f) * 2.5f;                       // knots at -2.2 + 0.4*j
            float mf = floorf(t5);
            int   m  = (int)mf;
            float u  = t5 - mf;
            float u2 = u * u, u3 = u2 * u;
            float w  = 1.f - u;
            float P0 = u3 * (1.f / 6.f);
            float P3 = w * w * w * (1.f / 6.f);
            float P1 = (1.f / 6.f) + 0.5f * u + 0.5f * u2 - 0.5f * u3;
            float P2 = (4.f / 6.f) - u2 + 0.5f * u3;
            int c0 = m - 3;
            if ((unsigned)(c0 + 0) <= 7u) row[1 + c0 + 0] = f2bf(P3);
            if ((unsigned)(c0 + 1) <= 7u) row[1 + c0 + 1] = f2bf(P2);
            if ((unsigned)(c0 + 2) <= 7u) row[1 + c0 + 2] = f2bf(P1);
            if ((unsigned)(c0 + 3) <= 7u) row[1 + c0 + 3] = f2bf(P0);
        }
    }
    __syncthreads();

    // ---- K-loop: quadrant (32o x 32l), 2-way split-K, 1-ahead VGPR pipeline ----
    int ch0 = ks ? 40 : 0;
    int nch = ks ? 41 : 40;

    f32x4 acc00 = (f32x4){0.f, 0.f, 0.f, 0.f};
    f32x4 acc01 = acc00, acc10 = acc00, acc11 = acc00;

    int kk = ch0 / 9, jb = ch0 - kk * 9;
    const unsigned short* wp = Wf + (size_t)ch0 * 2048 + (size_t)(mq * 2) * 512 + (size_t)lane * 8;
    const unsigned short* fp = f2t + (size_t)(nq * 32 + lo + kk) * F2COLS + jb * 32 + hi * 8;

    bf16x8 a0 = *(const bf16x8*)(wp);
    bf16x8 a1 = *(const bf16x8*)(wp + 512);
    bf16x8 b0 = *(const bf16x8*)(fp);
    bf16x8 b1 = *(const bf16x8*)(fp + 16 * F2COLS);

#pragma unroll 2
    for (int t = 0; t < nch; ++t) {
        // advance to chunk t+1
        wp += 2048;
        jb += 1;
        fp += (jb == 9) ? (F2COLS - 8 * 32) : 32;
        if (jb == 9) jb = 0;
        bf16x8 na0, na1, nb0, nb1;
        if (t + 1 < nch) {
            na0 = *(const bf16x8*)(wp);
            na1 = *(const bf16x8*)(wp + 512);
            nb0 = *(const bf16x8*)(fp);
            nb1 = *(const bf16x8*)(fp + 16 * F2COLS);
        } else {
            na0 = a0; na1 = a1; nb0 = b0; nb1 = b1;
        }
        __builtin_amdgcn_s_setprio(1);
        acc00 = __builtin_amdgcn_mfma_f32_16x16x32_bf16(a0, b0, acc00, 0, 0, 0);
        acc01 = __builtin_amdgcn_mfma_f32_16x16x32_bf16(a0, b1, acc01, 0, 0, 0);
        acc10 = __builtin_amdgcn_mfma_f32_16x16x32_bf16(a1, b0, acc10, 0, 0, 0);
        acc11 = __builtin_amdgcn_mfma_f32_16x16x32_bf16(a1, b1, acc11, 0, 0, 0);
        __builtin_amdgcn_s_setprio(0);
        a0 = na0; a1 = na1; b0 = nb0; b1 = nb1;
    }

    // ---- 2-way cross-wave reduction: ks=1 writes 16KB, ks=0 sums + stores ----
    __syncthreads();   // all waves done reading f2t
    float* red  = (float*)smem;
    float* slot = red + ((size_t)(q * 4) * 64 + lane) * 4;   // 4 subtiles x 256 floats
    if (ks == 1) {
        *(f32x4*)(slot + 0)   = acc00;
        *(f32x4*)(slot + 256) = acc01;
        *(f32x4*)(slot + 512) = acc10;
        *(f32x4*)(slot + 768) = acc11;
    }
    __syncthreads();
    if (ks == 0) {
        f32x4 s00 = acc00 + *(const f32x4*)(slot + 0);
        f32x4 s01 = acc01 + *(const f32x4*)(slot + 256);
        f32x4 s10 = acc10 + *(const f32x4*)(slot + 512);
        f32x4 s11 = acc11 + *(const f32x4*)(slot + 768);
        int obase = mq * 32 + hi * 4;
        int lbase = l0 + nq * 32 + lo;
        float* op0 = out + ((size_t)b * KOUT + obase) * LIN + lbase;        // dm=0
        float* op1 = out + ((size_t)b * KOUT + obase + 16) * LIN + lbase;   // dm=1
#pragma unroll
        for (int r = 0; r < 4; ++r) {
            op0[(size_t)r * LIN]      = s00[r];
            op0[(size_t)r * LIN + 16] = s01[r];
            op1[(size_t)r * LIN]      = s10[r];
            op1[(size_t)r * LIN + 16] = s11[r];
        }
    }
}

} // namespace

extern "C" void kernel_launch(void* const* d_in, const int* in_sizes, int n_in,
                              void* d_out, int out_size, void* d_ws, size_t ws_size,
                              hipStream_t stream) {
    const float* x             = (const float*)d_in[0];
    const float* base_w        = (const float*)d_in[1];
    const float* spline_w      = (const float*)d_in[2];
    const float* spline_scaler = (const float*)d_in[3];
    float* out = (float*)d_out;

    unsigned short* Wf = (unsigned short*)d_ws;   // 81*4*64*8 u16 = 331776 B

    kan_wprep<<<(KOUT * KIN * KW + 255) / 256, 256, 0, stream>>>(base_w, spline_w, spline_scaler, Wf);
    kan_fused<<<512, 512, 0, stream>>>(x, Wf, out);
}

// Round 8
// 22.974 us; speedup vs baseline: 1.1055x; 1.1055x over previous
//
#include <hip/hip_runtime.h>
#include <hip/hip_bf16.h>

namespace {

constexpr int KIN  = 32;    // IN_CH
constexpr int KOUT = 64;    // OUT_CH
constexpr int KW   = 9;     // KERNEL
constexpr int KPAD = 4;     // PADDING
constexpr int LIN  = 2048;
constexpr int KTOT = 2592;  // 9 taps * 288 features

typedef __bf16 bf16x8 __attribute__((ext_vector_type(8)));
typedef float  f32x4  __attribute__((ext_vector_type(4)));

__device__ __forceinline__ unsigned short f2bf(float x) {
    unsigned int u = __float_as_uint(x);
    u += 0x7FFFu + ((u >> 16) & 1u);   // RNE
    return (unsigned short)(u >> 16);
}

// ---- kernel 1: weights -> MFMA-fragment order ----
// Wf[((ch*4+m)*64 + hi*16+lo)*8 + e] = W[o=m*16+lo][kappa=ch*32+hi*8+e]
__global__ __launch_bounds__(256) void kan_wprep(const float* __restrict__ base_w,
                                                 const float* __restrict__ spline_w,
                                                 const float* __restrict__ spline_scaler,
                                                 unsigned short* __restrict__ Wf) {
    int t = blockIdx.x * 256 + threadIdx.x;
    if (t >= KOUT * KIN * KW) return;
    int k = t % KW;
    int i = (t / KW) % KIN;
    int o = t / (KW * KIN);
    float sc = spline_scaler[t];
    int m  = o >> 4;
    int lo = o & 15;
#pragma unroll
    for (int c = 0; c < 9; ++c) {
        float val = (c == 0) ? base_w[t] : spline_w[(size_t)t * 8 + (c - 1)] * sc;
        int kappa = k * 288 + i * 9 + c;
        int ch = kappa >> 5;
        int hi = (kappa & 31) >> 3;
        int e  = kappa & 7;
        Wf[((size_t)(ch * 4 + m) * 64 + hi * 16 + lo) * 8 + e] = f2bf(val);
    }
}

// ---- kernel 2: fused features + barrier-free 8-way split-K, pipelined ----
constexpr int BN     = 64;
constexpr int TROW   = 72;    // BN + KW - 1
constexpr int F2COLS = 296;   // 592B rows; stride 148 dw = 20 mod 32 (2-way max, free)

__global__ __launch_bounds__(512, 4) void kan_fused(const float* __restrict__ x,
                                                    const unsigned short* __restrict__ Wf,
                                                    float* __restrict__ out) {
    __shared__ char smem[65536];                 // f2t (42.6KB) / red (64KB, aliased)
    unsigned short* f2t = (unsigned short*)smem;
    float*          red = (float*)smem;

    int tid  = threadIdx.x;
    int lane = tid & 63;
    int wv   = tid >> 6;          // 0..7
    int lo = lane & 15, hi = lane >> 4;

    int blk = blockIdx.x;
    int b   = blk >> 5;
    int l0  = (blk & 31) * BN;

    // ---- hoist x loads (long latency) ahead of LDS zeroing ----
    float vv[5];
#pragma unroll
    for (int p = 0; p < 5; ++p) {
        int unit = p * 512 + tid;
        bool ok = unit < TROW * KIN;
        int i = unit / TROW;
        int r = unit - i * TROW;
        int gx = l0 + r - KPAD;
        vv[p] = 0.f;
        if (ok && gx >= 0 && gx < LIN) vv[p] = x[((size_t)b * KIN + i) * LIN + gx];
    }

    // ---- zero f2t (2664 x 16B) ----
    {
        f32x4 z = (f32x4){0.f, 0.f, 0.f, 0.f};
        for (int c = tid; c < TROW * F2COLS / 8; c += 512)
            *(f32x4*)(f2t + (size_t)c * 8) = z;
    }
    __syncthreads();

    // ---- features: silu + closed-form cubic B-spline, scatter to LDS ----
#pragma unroll
    for (int p = 0; p < 5; ++p) {
        int unit = p * 512 + tid;
        bool ok = unit < TROW * KIN;
        int i = unit / TROW;
        int r = unit - i * TROW;
        float v = vv[p];
        if (ok) {
            unsigned short* row = f2t + (size_t)r * F2COLS + i * 9;
            row[0] = f2bf(v / (1.f + __expf(-v)));             // silu
            float t5 = (v + 2.2f) * 2.5f;                       // knots at -2.2 + 0.4*j
            float mf = floorf(t5);
            int   m  = (int)mf;
            float u  = t5 - mf;
            float u2 = u * u, u3 = u2 * u;
            float w  = 1.f - u;
            float P0 = u3 * (1.f / 6.f);
            float P3 = w * w * w * (1.f / 6.f);
            float P1 = (1.f / 6.f) + 0.5f * u + 0.5f * u2 - 0.5f * u3;
            float P2 = (4.f / 6.f) - u2 + 0.5f * u3;
            int c0 = m - 3;
            if ((unsigned)(c0 + 0) <= 7u) row[1 + c0 + 0] = f2bf(P3);
            if ((unsigned)(c0 + 1) <= 7u) row[1 + c0 + 1] = f2bf(P2);
            if ((unsigned)(c0 + 2) <= 7u) row[1 + c0 + 2] = f2bf(P1);
            if ((unsigned)(c0 + 3) <= 7u) row[1 + c0 + 3] = f2bf(P0);
        }
    }
    __syncthreads();

    // ---- 8-way split-K: wave wv owns chunks [ch0, ch0+nch) of 81 ----
    int nch = (wv == 0) ? 11 : 10;
    int ch0 = (wv == 0) ? 0 : 10 * wv + 1;

    f32x4 acc[4][4];
#pragma unroll
    for (int m = 0; m < 4; ++m)
#pragma unroll
        for (int n = 0; n < 4; ++n) acc[m][n] = (f32x4){0.f, 0.f, 0.f, 0.f};

    int kk = ch0 / 9;
    int jb = ch0 - kk * 9;
    const unsigned short* wp = Wf + (size_t)ch0 * 2048 + (size_t)lane * 8;
    const unsigned short* fp = f2t + (size_t)(lo + kk) * F2COLS + jb * 32 + hi * 8;

    // prime chunk ch0
    bf16x8 a0 = *(const bf16x8*)(wp);
    bf16x8 a1 = *(const bf16x8*)(wp + 512);
    bf16x8 a2 = *(const bf16x8*)(wp + 1024);
    bf16x8 a3 = *(const bf16x8*)(wp + 1536);
    bf16x8 b0 = *(const bf16x8*)(fp);
    bf16x8 b1 = *(const bf16x8*)(fp + 16 * F2COLS);
    bf16x8 b2 = *(const bf16x8*)(fp + 32 * F2COLS);
    bf16x8 b3 = *(const bf16x8*)(fp + 48 * F2COLS);

    for (int t = 0; t < nch; ++t) {
        // next-chunk pointers (clamped on last iteration -> harmless reload)
        bool last = (t + 1 == nch);
        const unsigned short* wpn = last ? wp : wp + 2048;
        int jb2 = last ? jb : jb + 1;
        const unsigned short* fpn = last ? fp : fp + ((jb2 == 9) ? (F2COLS - 8 * 32) : 32);
        if (jb2 == 9) jb2 = 0;

        // prefetch A(t+1) early: full MFMA block below hides L2 latency
        bf16x8 na0 = *(const bf16x8*)(wpn);
        bf16x8 na1 = *(const bf16x8*)(wpn + 512);
        bf16x8 na2 = *(const bf16x8*)(wpn + 1024);
        bf16x8 na3 = *(const bf16x8*)(wpn + 1536);

        __builtin_amdgcn_s_setprio(1);
        // n-major: finish consumers of b_n, then reload b_n in place for t+1
        acc[0][0] = __builtin_amdgcn_mfma_f32_16x16x32_bf16(a0, b0, acc[0][0], 0, 0, 0);
        acc[1][0] = __builtin_amdgcn_mfma_f32_16x16x32_bf16(a1, b0, acc[1][0], 0, 0, 0);
        acc[2][0] = __builtin_amdgcn_mfma_f32_16x16x32_bf16(a2, b0, acc[2][0], 0, 0, 0);
        acc[3][0] = __builtin_amdgcn_mfma_f32_16x16x32_bf16(a3, b0, acc[3][0], 0, 0, 0);
        b0 = *(const bf16x8*)(fpn);
        acc[0][1] = __builtin_amdgcn_mfma_f32_16x16x32_bf16(a0, b1, acc[0][1], 0, 0, 0);
        acc[1][1] = __builtin_amdgcn_mfma_f32_16x16x32_bf16(a1, b1, acc[1][1], 0, 0, 0);
        acc[2][1] = __builtin_amdgcn_mfma_f32_16x16x32_bf16(a2, b1, acc[2][1], 0, 0, 0);
        acc[3][1] = __builtin_amdgcn_mfma_f32_16x16x32_bf16(a3, b1, acc[3][1], 0, 0, 0);
        b1 = *(const bf16x8*)(fpn + 16 * F2COLS);
        acc[0][2] = __builtin_amdgcn_mfma_f32_16x16x32_bf16(a0, b2, acc[0][2], 0, 0, 0);
        acc[1][2] = __builtin_amdgcn_mfma_f32_16x16x32_bf16(a1, b2, acc[1][2], 0, 0, 0);
        acc[2][2] = __builtin_amdgcn_mfma_f32_16x16x32_bf16(a2, b2, acc[2][2], 0, 0, 0);
        acc[3][2] = __builtin_amdgcn_mfma_f32_16x16x32_bf16(a3, b2, acc[3][2], 0, 0, 0);
        b2 = *(const bf16x8*)(fpn + 32 * F2COLS);
        acc[0][3] = __builtin_amdgcn_mfma_f32_16x16x32_bf16(a0, b3, acc[0][3], 0, 0, 0);
        acc[1][3] = __builtin_amdgcn_mfma_f32_16x16x32_bf16(a1, b3, acc[1][3], 0, 0, 0);
        acc[2][3] = __builtin_amdgcn_mfma_f32_16x16x32_bf16(a2, b3, acc[2][3], 0, 0, 0);
        acc[3][3] = __builtin_amdgcn_mfma_f32_16x16x32_bf16(a3, b3, acc[3][3], 0, 0, 0);
        b3 = *(const bf16x8*)(fpn + 48 * F2COLS);
        __builtin_amdgcn_s_setprio(0);

        a0 = na0; a1 = na1; a2 = na2; a3 = na3;
        wp = wpn; fp = fpn; jb = jb2;
    }

    // ---- 8-way cross-wave reduction, two 64KB phases over dead f2t ----
    __syncthreads();   // all waves done reading f2t
#pragma unroll
    for (int mp = 0; mp < 2; ++mp) {
#pragma unroll
        for (int dm = 0; dm < 2; ++dm)
#pragma unroll
            for (int n = 0; n < 4; ++n)
                *(f32x4*)(red + (((size_t)wv * 8 + dm * 4 + n) * 64 + lane) * 4) = acc[mp * 2 + dm][n];
        __syncthreads();
        {
            int dm = wv >> 2, n = wv & 3;
            f32x4 s = (f32x4){0.f, 0.f, 0.f, 0.f};
#pragma unroll
            for (int w = 0; w < 8; ++w)
                s += *(const f32x4*)(red + (((size_t)w * 8 + dm * 4 + n) * 64 + lane) * 4);
            int o = (mp * 2 + dm) * 16 + hi * 4;
            float* op = out + ((size_t)b * KOUT + o) * LIN + l0 + n * 16 + lo;
            op[0]          = s[0];
            op[LIN]        = s[1];
            op[2 * LIN]    = s[2];
            op[3 * (size_t)LIN] = s[3];
        }
        if (mp == 0) __syncthreads();
    }
}

} // namespace

extern "C" void kernel_launch(void* const* d_in, const int* in_sizes, int n_in,
                              void* d_out, int out_size, void* d_ws, size_t ws_size,
                              hipStream_t stream) {
    const float* x             = (const float*)d_in[0];
    const float* base_w        = (const float*)d_in[1];
    const float* spline_w      = (const float*)d_in[2];
    const float* spline_scaler = (const float*)d_in[3];
    float* out = (float*)d_out;

    unsigned short* Wf = (unsigned short*)d_ws;   // 81*4*64*8 u16 = 331776 B

    kan_wprep<<<(KOUT * KIN * KW + 255) / 256, 256, 0, stream>>>(base_w, spline_w, spline_scaler, Wf);
    kan_fused<<<512, 512, 0, stream>>>(x, Wf, out);
}